// Round 2
// baseline (250.978 us; speedup 1.0000x reference)
//
#include <hip/hip_runtime.h>
#include <hip/hip_bf16.h>

#define NN 50000
#define NE 800000
#define DD 128
#define NCLS 40
#define NBK ((NN + 255) >> 8)      // 196 dst-buckets of 256 nodes
#define EPB 1024                   // edges per k_part block (4/thread)
#define PB ((NE + EPB - 1) / EPB)  // 782 partition blocks
#define CVB ((NN * DD / 4) / 256)  // 6250 cvt blocks
#define WB 384                     // weight-convert blocks (192 units x 2 halves)
#define SEMAX 5120                 // max edges per bucket (mean 4081, sd 64)

typedef _Float16 f16x8 __attribute__((ext_vector_type(8)));  // 8 f16 (4 VGPRs)
typedef _Float16 f16x4 __attribute__((ext_vector_type(4)));
typedef float f32x4 __attribute__((ext_vector_type(4)));     // MFMA acc

__device__ __forceinline__ unsigned int pack2h(_Float16 a, _Float16 b) {
    union { _Float16 h[2]; unsigned int u; } c;
    c.h[0] = a; c.h[1] = b;
    return c.u;
}
__device__ __forceinline__ void unpack2h(unsigned int p, float& a, float& b) {
    union { unsigned int u; _Float16 h[2]; } c;
    c.u = p;
    a = (float)c.h[0]; b = (float)c.h[1];
}

// ---------------------------------------------------------------------------
// Mega front kernel.
//   Blocks [0,PB):            LDS bucket-sort of 1024 edges -> dense chunk
//   Blocks [PB,PB+CVB):       x fp32 -> f16 hi plane
//   Blocks [PB+CVB,+WB):      all 3 layers' B -> MFMA-fragment-major f16
__global__ void k_front(const int* __restrict__ ei, int* __restrict__ cellcnt,
                        int* __restrict__ celloff, unsigned int* __restrict__ pairs,
                        const float* __restrict__ x, unsigned short* __restrict__ xh,
                        const float* __restrict__ w1l, const float* __restrict__ w1r,
                        const float* __restrict__ w2l, const float* __restrict__ w2r,
                        const float* __restrict__ w3l, const float* __restrict__ w3r,
                        unsigned short* __restrict__ bt1h,
                        unsigned short* __restrict__ bt2h,
                        unsigned short* __restrict__ bt3h) {
    if (blockIdx.x >= PB + CVB) {
        // ---- weight conversion (f16 hi only; error budget covers it) ----
        int idx = blockIdx.x - (PB + CVB);
        int w = idx >> 1, half = idx & 1;
        int ks = w & 7, tmp = w >> 3;
        int nt = tmp & 7, layer = tmp >> 3;
        const int NT = (layer == 2) ? 3 : 8;
        const int NC = (layer == 2) ? NCLS : DD;
        if (nt >= NT) return;
        const float* wl = (layer == 0) ? w1l : (layer == 1) ? w2l : w3l;
        const float* wr = (layer == 0) ? w1r : (layer == 1) ? w2r : w3r;
        unsigned short* bh = (layer == 0) ? bt1h : (layer == 1) ? bt2h : bt3h;
        int t = threadIdx.x;
        int j = t & 7, lane = (t >> 3) + half * 32;
        int row = nt * 16 + (lane & 15);          // output column n
        int k = ks * 32 + (lane >> 4) * 8 + j;    // K position in [Wl;Wr]
        float v = 0.f;
        if (row < NC)
            v = (k < 128) ? wl[(size_t)k * NC + row] : wr[(size_t)(k - 128) * NC + row];
        union { _Float16 f; unsigned short u; } ch;
        ch.f = (_Float16)v;
        bh[((size_t)(ks * NT + nt) * 64 + lane) * 8 + j] = ch.u;
        return;
    }
    if (blockIdx.x >= PB) {
        // ---- x conversion ----
        int i = (blockIdx.x - PB) * 256 + threadIdx.x;
        float4 v = ((const float4*)x)[i];
        f16x4 h;
        h[0] = (_Float16)v.x; h[1] = (_Float16)v.y;
        h[2] = (_Float16)v.z; h[3] = (_Float16)v.w;
        *(f16x4*)(xh + (size_t)i * 4) = h;
        return;
    }
    // ---- edge partition: LDS bucket-sort, dense chunk out ----
    __shared__ int hist[NBK];
    __shared__ int s[256];
    __shared__ unsigned int sE[EPB];
    __shared__ int nz;
    const int t = threadIdx.x, blk = blockIdx.x;
    const int e0 = blk * EPB;
    if (t == 0) nz = 0;
    for (int i = t; i < NBK; i += 256) hist[i] = 0;
    __syncthreads();
    int any = 0;
    for (int i = t; i < EPB; i += 256)
        if (ei[2 * e0 + 2 * i + 1] != 0) any = 1;
    if (any) atomicOr(&nz, 1);
    __syncthreads();
    const int is64 = (nz == 0);
    unsigned int v[EPB / 256];
    int eb[EPB / 256], er[EPB / 256];
#pragma unroll
    for (int j = 0; j < EPB / 256; ++j) {
        int e = e0 + j * 256 + t;
        if (e < NE) {
            int sv, d;
            if (is64) { sv = ei[2 * e]; d = ei[2 * (NE + e)]; }
            else      { sv = ei[e];     d = ei[NE + e]; }
            v[j] = ((unsigned)sv << 16) | (unsigned)d;
            eb[j] = d >> 8;
            er[j] = atomicAdd(&hist[eb[j]], 1);
        } else {
            eb[j] = -1;
        }
    }
    __syncthreads();
    int hv = (t < NBK) ? hist[t] : 0;
    s[t] = hv;
    __syncthreads();
#pragma unroll
    for (int off = 1; off < 256; off <<= 1) {
        int u = (t >= off) ? s[t - off] : 0;
        __syncthreads();
        s[t] += u;
        __syncthreads();
    }
#pragma unroll
    for (int j = 0; j < EPB / 256; ++j)
        if (eb[j] >= 0) sE[s[eb[j]] - hist[eb[j]] + er[j]] = v[j];
    __syncthreads();
    ((uint4*)(pairs + (size_t)blk * EPB))[t] = ((const uint4*)sE)[t];
    for (int i = t; i < NBK; i += 256) {
        cellcnt[(size_t)i * PB + blk] = hist[i];
        celloff[(size_t)i * PB + blk] = s[i] - hist[i];
    }
}

// Bucket totals: 196 blocks, block b reduces its (coalesced) cellcnt row.
__global__ void k_scan_ba(const int* __restrict__ cellcnt, int* __restrict__ bsum) {
    __shared__ int red[256];
    int b = blockIdx.x, t = threadIdx.x;
    int acc = 0;
    for (int i = t; i < PB; i += 256) acc += cellcnt[(size_t)b * PB + i];
    red[t] = acc;
    __syncthreads();
#pragma unroll
    for (int off = 128; off > 0; off >>= 1) {
        if (t < off) red[t] += red[t + off];
        __syncthreads();
    }
    if (t == 0) bsum[b] = red[0];
}

// Phase 2 (+ folded bucket-base scan): one 512-thread block per bucket.
// (Reverted to 256-key scatter: round-1 showed intra-node src ordering is
// irrelevant at mean degree 16 — no locality to manufacture.)
__global__ void k_fill2(const unsigned int* __restrict__ pairs,
                        const int* __restrict__ cellcnt,
                        const int* __restrict__ celloff,
                        const int* __restrict__ bsum,
                        int* __restrict__ row_ptr, int* __restrict__ srcs) {
    __shared__ unsigned int sE[SEMAX];
    __shared__ int hist[256];
    __shared__ int cur[256];
    __shared__ int sb[256];
    __shared__ int scnt;
    const int b = blockIdx.x, t = threadIdx.x;
    if (t < 256) {
        int v = (t < NBK) ? bsum[t] : 0;
        sb[t] = v;
    }
    if (t == 0) scnt = 0;
    if (t < 256) hist[t] = 0;
    __syncthreads();
#pragma unroll
    for (int off = 1; off < 256; off <<= 1) {
        int u = (t >= off && t < 256) ? sb[t - off] : 0;
        __syncthreads();
        if (t < 256) sb[t] += u;
        __syncthreads();
    }
    const int bbase = (b == 0) ? 0 : sb[b - 1];
    if (b == NBK - 1 && t == 0) row_ptr[NN] = sb[NBK - 1];
    for (int blk = t; blk < PB; blk += 512) {
        int cnt = cellcnt[(size_t)b * PB + blk];
        if (cnt) {
            int off = celloff[(size_t)b * PB + blk];
            int base = atomicAdd(&scnt, cnt);
            if (base + cnt <= SEMAX) {
                const unsigned int* pp = pairs + (size_t)blk * EPB + off;
                for (int j = 0; j < cnt; ++j) {
                    unsigned int v = pp[j];
                    sE[base + j] = v;
                    atomicAdd(&hist[v & 255u], 1);
                }
            }
        }
    }
    __syncthreads();
    int h = (t < 256) ? hist[t] : 0;
    if (t < 256) cur[t] = h;
    __syncthreads();
#pragma unroll
    for (int off = 1; off < 256; off <<= 1) {
        int u = (t >= off && t < 256) ? cur[t - off] : 0;
        __syncthreads();
        if (t < 256) cur[t] += u;
        __syncthreads();
    }
    if (t < 256) {
        int node = (b << 8) + t;
        int base = bbase + cur[t] - h;
        if (node < NN) row_ptr[node] = base;
        cur[t] = base;
    }
    __syncthreads();
    int total = min(scnt, SEMAX);
    for (int i = t; i < total; i += 512) {
        unsigned int v = sE[i];
        int pos = atomicAdd(&cur[v & 255u], 1);
        srcs[pos] = (int)(v >> 16);
    }
}

// ---------------------------------------------------------------------------
// Fused mean-aggregate + MFMA GEMM (layers 1-2).
// Phase 1: wave w gathers+averages exactly the 16 rows it will consume as
//          MFMA A-operands (k<128 half) into LDS sA (stride 68 u32: 2-way
//          banks on b128 reads, free). No cross-wave sync needed for sA.
// Phase 2: B staged 2-ks at a time (16 KB); self rows (k>=128) preloaded to
//          registers; standard 16x16x32 f16 MFMA, NT=8.
__global__ __launch_bounds__(256, 4)
void k_fuse(const unsigned int* __restrict__ inh, const int* __restrict__ row_ptr,
            const int* __restrict__ srcs, const unsigned short* __restrict__ Bthf,
            const float* __restrict__ bias, unsigned short* __restrict__ outh) {
    __shared__ unsigned int sAu[64 * 68];        // 17.4 KB, padded stride
    __shared__ unsigned short sBh[2 * 8 * 64 * 8];  // 16 KB (2 ks-steps)

    const int tid = threadIdx.x;
    const int wave = tid >> 6, lane = tid & 63;
    const int quad = lane >> 4, mr = lane & 15;
    const int m0b = blockIdx.x * 64;
    const int nw0 = m0b + wave * 16;

    // --- phase 1: gather + mean for this wave's 16 rows ---
    int rp = row_ptr[min(nw0 + min(lane, 16), NN)];  // 17 entries via lanes
    for (int ni = 0; ni < 16; ++ni) {
        int node = nw0 + ni;
        unsigned int packed = 0u;
        if (node < NN) {
            int b = __shfl(rp, ni), e = __shfl(rp, ni + 1);
            float a0 = 0.f, a1 = 0.f;
            int nfull = (e - b) & ~7;
            int i = b;
            for (; i < b + nfull; i += 8) {
                unsigned int p0 = inh[(size_t)srcs[i + 0] * 64 + lane];
                unsigned int p1 = inh[(size_t)srcs[i + 1] * 64 + lane];
                unsigned int p2 = inh[(size_t)srcs[i + 2] * 64 + lane];
                unsigned int p3 = inh[(size_t)srcs[i + 3] * 64 + lane];
                unsigned int p4 = inh[(size_t)srcs[i + 4] * 64 + lane];
                unsigned int p5 = inh[(size_t)srcs[i + 5] * 64 + lane];
                unsigned int p6 = inh[(size_t)srcs[i + 6] * 64 + lane];
                unsigned int p7 = inh[(size_t)srcs[i + 7] * 64 + lane];
                float u0, u1;
                unpack2h(p0, u0, u1); a0 += u0; a1 += u1;
                unpack2h(p1, u0, u1); a0 += u0; a1 += u1;
                unpack2h(p2, u0, u1); a0 += u0; a1 += u1;
                unpack2h(p3, u0, u1); a0 += u0; a1 += u1;
                unpack2h(p4, u0, u1); a0 += u0; a1 += u1;
                unpack2h(p5, u0, u1); a0 += u0; a1 += u1;
                unpack2h(p6, u0, u1); a0 += u0; a1 += u1;
                unpack2h(p7, u0, u1); a0 += u0; a1 += u1;
            }
            int rem = e - i;
            if (rem > 0) {
                unsigned int p[8];
#pragma unroll
                for (int j = 0; j < 8; ++j) {
                    int idx = i + j;
                    if (idx > e - 1) idx = e - 1;
                    p[j] = inh[(size_t)srcs[idx] * 64 + lane];
                }
#pragma unroll
                for (int j = 0; j < 8; ++j) {
                    float u0, u1;
                    unpack2h(p[j], u0, u1);
                    if (j < rem) { a0 += u0; a1 += u1; }
                }
            }
            int deg = e - b;
            float inv = 1.0f / (float)(deg > 0 ? deg : 1);
            packed = pack2h((_Float16)(a0 * inv), (_Float16)(a1 * inv));
        }
        sAu[(wave * 16 + ni) * 68 + lane] = packed;
    }

    // --- self fragments (k>=128), straight from global ---
    const unsigned short* inh16 = (const unsigned short*)inh;
    const int row = nw0 + mr;
    const bool rok = row < NN;
    const f16x8 zero = {};
    f16x8 self[4];
#pragma unroll
    for (int j = 0; j < 4; ++j)
        self[j] = rok ? *(const f16x8*)(inh16 + (size_t)row * 128 + j * 32 + quad * 8)
                      : zero;

    f32x4 acc[8] = {};
    const int arow = (wave * 16 + mr) * 68;

#pragma unroll
    for (int s = 0; s < 4; ++s) {
        const uint4* gh = (const uint4*)(Bthf + (size_t)s * (2 * 8 * 64 * 8));
        uint4* lh = (uint4*)sBh;
        if (s) __syncthreads();
        for (int i = tid; i < 1024; i += 256) lh[i] = gh[i];
        __syncthreads();
#pragma unroll
        for (int kl = 0; kl < 2; ++kl) {
            const int ks = s * 2 + kl;
            f16x8 ah;
            if (ks < 4)
                ah = *(const f16x8*)(&sAu[arow + ks * 16 + quad * 4]);
            else
                ah = self[ks - 4];
#pragma unroll
            for (int n = 0; n < 8; ++n) {
                f16x8 bh = *(const f16x8*)(sBh + ((kl * 8 + n) * 64 + lane) * 8);
                acc[n] = __builtin_amdgcn_mfma_f32_16x16x32_f16(ah, bh, acc[n], 0, 0, 0);
            }
        }
    }

    // Epilogue. C/D layout: col = lane&15, row = quad*4 + reg.
#pragma unroll
    for (int n = 0; n < 8; ++n) {
        int col = n * 16 + mr;
        float bv = bias[col];
#pragma unroll
        for (int r = 0; r < 4; ++r) {
            int orow = nw0 + quad * 4 + r;
            if (orow < NN) {
                float v = acc[n][r] + bv;
                v = v > 0.f ? v : 0.f;
                union { _Float16 f; unsigned short u; } ch;
                ch.f = (_Float16)v;
                outh[(size_t)orow * 128 + col] = ch.u;
            }
        }
    }
}

// ---------------------------------------------------------------------------
// Layer 3 pre-projection: z = h2 @ w3_l (f16, 64-col-padded rows),
//                         y = h2 @ w3_r + b3 (f32, 40 cols). k=128 only.
// Exploits mean-linearity: agg(h2) @ w3_l == agg(h2 @ w3_l).
__global__ __launch_bounds__(256, 4)
void k_gemm3(const unsigned short* __restrict__ Ah,
             const unsigned short* __restrict__ Bthf,
             const float* __restrict__ bias,
             unsigned short* __restrict__ zh, float* __restrict__ yf) {
    __shared__ unsigned short sBh[8 * 3 * 64 * 8];  // 24 KB, all of B
    const int tid = threadIdx.x;
    const int wave = tid >> 6, lane = tid & 63;
    const int quad = lane >> 4, mr = lane & 15;
    const int m0 = blockIdx.x * 64 + wave * 16;
    const int row = m0 + mr;
    const bool rok = row < NN;

    const uint4* gh = (const uint4*)Bthf;
    uint4* lh = (uint4*)sBh;
    for (int i = tid; i < (8 * 3 * 64 * 8) / 8; i += 256) lh[i] = gh[i];

    const f16x8 zero = {};
    f16x8 a[4];
#pragma unroll
    for (int j = 0; j < 4; ++j)
        a[j] = rok ? *(const f16x8*)(Ah + (size_t)row * 128 + j * 32 + quad * 8)
                   : zero;
    __syncthreads();

    f32x4 accl[3] = {}, accr[3] = {};
#pragma unroll
    for (int ks = 0; ks < 4; ++ks) {
#pragma unroll
        for (int n = 0; n < 3; ++n) {
            f16x8 bl = *(const f16x8*)(sBh + ((ks * 3 + n) * 64 + lane) * 8);
            accl[n] = __builtin_amdgcn_mfma_f32_16x16x32_f16(a[ks], bl, accl[n], 0, 0, 0);
            f16x8 br = *(const f16x8*)(sBh + (((ks + 4) * 3 + n) * 64 + lane) * 8);
            accr[n] = __builtin_amdgcn_mfma_f32_16x16x32_f16(a[ks], br, accr[n], 0, 0, 0);
        }
    }

#pragma unroll
    for (int n = 0; n < 3; ++n) {
        int col = n * 16 + mr;
        float bv = (col < NCLS) ? bias[col] : 0.f;
#pragma unroll
        for (int r = 0; r < 4; ++r) {
            int orow = m0 + quad * 4 + r;
            if (orow < NN) {
                union { _Float16 f; unsigned short u; } ch;
                ch.f = (_Float16)accl[n][r];
                zh[(size_t)orow * 64 + col] = ch.u;          // cols >=40 are 0 (B zero-padded)
                if (col < NCLS) yf[(size_t)orow * 40 + col] = accr[n][r] + bv;
            }
        }
    }
}

// ---------------------------------------------------------------------------
// Layer 3 aggregation over projected z (40 f16 = 20 u32, rows padded to
// 128 B): half-wave per node, lanes 0-31 of each half read u32 cols 0-31
// (exactly the 2 fetched lines; cols 20-31 discarded). out = relu(mean+y).
__global__ void k_agg3(const unsigned int* __restrict__ zu,
                       const int* __restrict__ row_ptr,
                       const int* __restrict__ srcs,
                       const float* __restrict__ yf, float* __restrict__ out) {
    const int tid = threadIdx.x;
    const int wave = tid >> 6, lane = tid & 63;
    const int half = lane >> 5, hl = lane & 31;
    const int node = blockIdx.x * 8 + wave * 2 + half;  // 6250*8 == NN exactly
    int b = row_ptr[node], e = row_ptr[node + 1];
    int deg = e - b;
    int od = __shfl_xor(deg, 32);
    int md = max(deg, od);
    int ce = (e > b) ? (e - 1) : b;  // clamp target (deg=0 -> dummy, masked)
    float a0 = 0.f, a1 = 0.f;
    for (int base = 0; base < md; base += 8) {
        unsigned int p[8];
#pragma unroll
        for (int j = 0; j < 8; ++j) {
            int idx = b + base + j;
            if (idx > ce) idx = ce;
            p[j] = zu[(size_t)srcs[idx] * 32 + hl];
        }
#pragma unroll
        for (int j = 0; j < 8; ++j) {
            float u0, u1;
            unpack2h(p[j], u0, u1);
            if (base + j < deg) { a0 += u0; a1 += u1; }
        }
    }
    float inv = 1.0f / (float)(deg > 0 ? deg : 1);
    if (hl < 20) {
        float2 yv = ((const float2*)yf)[(size_t)node * 20 + hl];
        float2 o;
        o.x = fmaxf(a0 * inv + yv.x, 0.f);
        o.y = fmaxf(a1 * inv + yv.y, 0.f);
        ((float2*)out)[(size_t)node * 20 + hl] = o;
    }
}

// ---------------------------------------------------------------------------
extern "C" void kernel_launch(void* const* d_in, const int* in_sizes, int n_in,
                              void* d_out, int out_size, void* d_ws, size_t ws_size,
                              hipStream_t stream) {
    const float* x    = (const float*)d_in[0];
    const int*   ei   = (const int*)d_in[1];
    const float* w1_l = (const float*)d_in[2];
    const float* w1_r = (const float*)d_in[3];
    const float* b1   = (const float*)d_in[4];
    const float* w2_l = (const float*)d_in[5];
    const float* w2_r = (const float*)d_in[6];
    const float* b2   = (const float*)d_in[7];
    const float* w3_l = (const float*)d_in[8];
    const float* w3_r = (const float*)d_in[9];
    const float* b3   = (const float*)d_in[10];
    float* out = (float*)d_out;

    char* w = (char*)d_ws;
    size_t off = 0;
    auto alloc = [&](size_t bytes) -> void* {
        void* p = w + off;
        off += (bytes + 255) / 256 * 256;
        return p;
    };
    int* row_ptr = (int*)alloc((size_t)(NN + 1) * 4);
    int* srcs    = (int*)alloc((size_t)NE * 4);
    int* cellcnt = (int*)alloc((size_t)NBK * PB * 4);
    int* celloff = (int*)alloc((size_t)NBK * PB * 4);
    int* bsum    = (int*)alloc((size_t)NBK * 4);
    unsigned int* pairs = (unsigned int*)alloc((size_t)PB * EPB * 4);
    unsigned short* xh   = (unsigned short*)alloc((size_t)NN * DD * 2);  // also h2h
    unsigned short* h1h  = (unsigned short*)alloc((size_t)NN * DD * 2);
    unsigned short* zh   = (unsigned short*)alloc((size_t)NN * 64 * 2);
    float*          yf   = (float*)alloc((size_t)NN * 40 * 4);
    unsigned short* bt1h = (unsigned short*)alloc((size_t)8 * 8 * 64 * 8 * 2);
    unsigned short* bt2h = (unsigned short*)alloc((size_t)8 * 8 * 64 * 8 * 2);
    unsigned short* bt3h = (unsigned short*)alloc((size_t)8 * 3 * 64 * 8 * 2);
    unsigned short* h2h = xh;  // x dead after layer-1 fused kernel
    (void)ws_size;

    k_front<<<PB + CVB + WB, 256, 0, stream>>>(ei, cellcnt, celloff, pairs, x, xh,
                                               w1_l, w1_r, w2_l, w2_r, w3_l, w3_r,
                                               bt1h, bt2h, bt3h);
    k_scan_ba<<<NBK, 256, 0, stream>>>(cellcnt, bsum);
    k_fill2<<<NBK, 512, 0, stream>>>(pairs, cellcnt, celloff, bsum, row_ptr, srcs);

    const int gmb = (NN + 63) / 64;  // 782 blocks of 64 rows
    // Layer 1 (fused agg+GEMM)
    k_fuse<<<gmb, 256, 0, stream>>>((const unsigned int*)xh, row_ptr, srcs,
                                    bt1h, b1, h1h);
    // Layer 2 (h2h aliases xh; x is dead)
    k_fuse<<<gmb, 256, 0, stream>>>((const unsigned int*)h1h, row_ptr, srcs,
                                    bt2h, b2, h2h);
    // Layer 3: pre-project then light aggregate
    k_gemm3<<<gmb, 256, 0, stream>>>(h2h, bt3h, b3, zh, yf);
    k_agg3<<<NN / 8, 256, 0, stream>>>((const unsigned int*)zh, row_ptr, srcs,
                                       yf, out);
}

// Round 3
// 232.722 us; speedup vs baseline: 1.0784x; 1.0784x over previous
//
#include <hip/hip_runtime.h>
#include <hip/hip_bf16.h>

#define NN 50000
#define NE 800000
#define DD 128
#define NCLS 40
#define NBK ((NN + 255) >> 8)      // 196 dst-buckets of 256 nodes
#define EPB 1024                   // edges per k_part block (4/thread)
#define PB ((NE + EPB - 1) / EPB)  // 782 partition blocks
#define CVB ((NN * DD / 4) / 256)  // 6250 cvt blocks
#define WB 384                     // weight-convert blocks (192 units x 2 halves)
#define SEMAX 5120                 // max edges per bucket (mean 4081, sd 64)

typedef _Float16 f16x8 __attribute__((ext_vector_type(8)));  // 8 f16 (4 VGPRs)
typedef _Float16 f16x4 __attribute__((ext_vector_type(4)));
typedef float f32x4 __attribute__((ext_vector_type(4)));     // MFMA acc

__device__ __forceinline__ unsigned int pack2h(_Float16 a, _Float16 b) {
    union { _Float16 h[2]; unsigned int u; } c;
    c.h[0] = a; c.h[1] = b;
    return c.u;
}
__device__ __forceinline__ void unpack2h(unsigned int p, float& a, float& b) {
    union { unsigned int u; _Float16 h[2]; } c;
    c.u = p;
    a = (float)c.h[0]; b = (float)c.h[1];
}

// ---------------------------------------------------------------------------
// Mega front kernel.
//   Blocks [0,PB):            LDS bucket-sort of 1024 edges -> dense chunk
//   Blocks [PB,PB+CVB):       x fp32 -> f16 hi plane
//   Blocks [PB+CVB,+WB):      all 3 layers' B -> MFMA-fragment-major f16
__global__ void k_front(const int* __restrict__ ei, int* __restrict__ cellcnt,
                        int* __restrict__ celloff, unsigned int* __restrict__ pairs,
                        const float* __restrict__ x, unsigned short* __restrict__ xh,
                        const float* __restrict__ w1l, const float* __restrict__ w1r,
                        const float* __restrict__ w2l, const float* __restrict__ w2r,
                        const float* __restrict__ w3l, const float* __restrict__ w3r,
                        unsigned short* __restrict__ bt1h,
                        unsigned short* __restrict__ bt2h,
                        unsigned short* __restrict__ bt3h) {
    if (blockIdx.x >= PB + CVB) {
        // ---- weight conversion (f16 hi only; error budget covers it) ----
        int idx = blockIdx.x - (PB + CVB);
        int w = idx >> 1, half = idx & 1;
        int ks = w & 7, tmp = w >> 3;
        int nt = tmp & 7, layer = tmp >> 3;
        const int NT = (layer == 2) ? 3 : 8;
        const int NC = (layer == 2) ? NCLS : DD;
        if (nt >= NT) return;
        const float* wl = (layer == 0) ? w1l : (layer == 1) ? w2l : w3l;
        const float* wr = (layer == 0) ? w1r : (layer == 1) ? w2r : w3r;
        unsigned short* bh = (layer == 0) ? bt1h : (layer == 1) ? bt2h : bt3h;
        int t = threadIdx.x;
        int j = t & 7, lane = (t >> 3) + half * 32;
        int row = nt * 16 + (lane & 15);          // output column n
        int k = ks * 32 + (lane >> 4) * 8 + j;    // K position in [Wl;Wr]
        float v = 0.f;
        if (row < NC)
            v = (k < 128) ? wl[(size_t)k * NC + row] : wr[(size_t)(k - 128) * NC + row];
        union { _Float16 f; unsigned short u; } ch;
        ch.f = (_Float16)v;
        bh[((size_t)(ks * NT + nt) * 64 + lane) * 8 + j] = ch.u;
        return;
    }
    if (blockIdx.x >= PB) {
        // ---- x conversion ----
        int i = (blockIdx.x - PB) * 256 + threadIdx.x;
        float4 v = ((const float4*)x)[i];
        f16x4 h;
        h[0] = (_Float16)v.x; h[1] = (_Float16)v.y;
        h[2] = (_Float16)v.z; h[3] = (_Float16)v.w;
        *(f16x4*)(xh + (size_t)i * 4) = h;
        return;
    }
    // ---- edge partition: LDS bucket-sort, dense chunk out ----
    __shared__ int hist[NBK];
    __shared__ int s[256];
    __shared__ unsigned int sE[EPB];
    __shared__ int nz;
    const int t = threadIdx.x, blk = blockIdx.x;
    const int e0 = blk * EPB;
    if (t == 0) nz = 0;
    for (int i = t; i < NBK; i += 256) hist[i] = 0;
    __syncthreads();
    int any = 0;
    for (int i = t; i < EPB; i += 256)
        if (ei[2 * e0 + 2 * i + 1] != 0) any = 1;
    if (any) atomicOr(&nz, 1);
    __syncthreads();
    const int is64 = (nz == 0);
    unsigned int v[EPB / 256];
    int eb[EPB / 256], er[EPB / 256];
#pragma unroll
    for (int j = 0; j < EPB / 256; ++j) {
        int e = e0 + j * 256 + t;
        if (e < NE) {
            int sv, d;
            if (is64) { sv = ei[2 * e]; d = ei[2 * (NE + e)]; }
            else      { sv = ei[e];     d = ei[NE + e]; }
            v[j] = ((unsigned)sv << 16) | (unsigned)d;
            eb[j] = d >> 8;
            er[j] = atomicAdd(&hist[eb[j]], 1);
        } else {
            eb[j] = -1;
        }
    }
    __syncthreads();
    int hv = (t < NBK) ? hist[t] : 0;
    s[t] = hv;
    __syncthreads();
#pragma unroll
    for (int off = 1; off < 256; off <<= 1) {
        int u = (t >= off) ? s[t - off] : 0;
        __syncthreads();
        s[t] += u;
        __syncthreads();
    }
#pragma unroll
    for (int j = 0; j < EPB / 256; ++j)
        if (eb[j] >= 0) sE[s[eb[j]] - hist[eb[j]] + er[j]] = v[j];
    __syncthreads();
    ((uint4*)(pairs + (size_t)blk * EPB))[t] = ((const uint4*)sE)[t];
    for (int i = t; i < NBK; i += 256) {
        cellcnt[(size_t)i * PB + blk] = hist[i];
        celloff[(size_t)i * PB + blk] = s[i] - hist[i];
    }
}

// Bucket totals: 196 blocks, block b reduces its (coalesced) cellcnt row.
__global__ void k_scan_ba(const int* __restrict__ cellcnt, int* __restrict__ bsum) {
    __shared__ int red[256];
    int b = blockIdx.x, t = threadIdx.x;
    int acc = 0;
    for (int i = t; i < PB; i += 256) acc += cellcnt[(size_t)b * PB + i];
    red[t] = acc;
    __syncthreads();
#pragma unroll
    for (int off = 128; off > 0; off >>= 1) {
        if (t < off) red[t] += red[t + off];
        __syncthreads();
    }
    if (t == 0) bsum[b] = red[0];
}

// Phase 2 (+ folded bucket-base scan): one 512-thread block per bucket.
__global__ void k_fill2(const unsigned int* __restrict__ pairs,
                        const int* __restrict__ cellcnt,
                        const int* __restrict__ celloff,
                        const int* __restrict__ bsum,
                        int* __restrict__ row_ptr, int* __restrict__ srcs) {
    __shared__ unsigned int sE[SEMAX];
    __shared__ int hist[256];
    __shared__ int cur[256];
    __shared__ int sb[256];
    __shared__ int scnt;
    const int b = blockIdx.x, t = threadIdx.x;
    if (t < 256) {
        int v = (t < NBK) ? bsum[t] : 0;
        sb[t] = v;
    }
    if (t == 0) scnt = 0;
    if (t < 256) hist[t] = 0;
    __syncthreads();
#pragma unroll
    for (int off = 1; off < 256; off <<= 1) {
        int u = (t >= off && t < 256) ? sb[t - off] : 0;
        __syncthreads();
        if (t < 256) sb[t] += u;
        __syncthreads();
    }
    const int bbase = (b == 0) ? 0 : sb[b - 1];
    if (b == NBK - 1 && t == 0) row_ptr[NN] = sb[NBK - 1];
    for (int blk = t; blk < PB; blk += 512) {
        int cnt = cellcnt[(size_t)b * PB + blk];
        if (cnt) {
            int off = celloff[(size_t)b * PB + blk];
            int base = atomicAdd(&scnt, cnt);
            if (base + cnt <= SEMAX) {
                const unsigned int* pp = pairs + (size_t)blk * EPB + off;
                for (int j = 0; j < cnt; ++j) {
                    unsigned int v = pp[j];
                    sE[base + j] = v;
                    atomicAdd(&hist[v & 255u], 1);
                }
            }
        }
    }
    __syncthreads();
    int h = (t < 256) ? hist[t] : 0;
    if (t < 256) cur[t] = h;
    __syncthreads();
#pragma unroll
    for (int off = 1; off < 256; off <<= 1) {
        int u = (t >= off && t < 256) ? cur[t - off] : 0;
        __syncthreads();
        if (t < 256) cur[t] += u;
        __syncthreads();
    }
    if (t < 256) {
        int node = (b << 8) + t;
        int base = bbase + cur[t] - h;
        if (node < NN) row_ptr[node] = base;
        cur[t] = base;
    }
    __syncthreads();
    int total = min(scnt, SEMAX);
    for (int i = t; i < total; i += 512) {
        unsigned int v = sE[i];
        int pos = atomicAdd(&cur[v & 255u], 1);
        srcs[pos] = (int)(v >> 16);
    }
}

// ---------------------------------------------------------------------------
// Mean aggregation, hi-plane in -> hi-plane out. One wave per node; 16-deep
// load ILP (latency-bound gather wants max outstanding misses) + clamped tail.
__global__ __launch_bounds__(256, 8)
void k_agg(const unsigned int* __restrict__ inh, const int* __restrict__ row_ptr,
           const int* __restrict__ srcs, unsigned int* __restrict__ oh) {
    int node = blockIdx.x * 4 + (threadIdx.x >> 6);
    if (node >= NN) return;
    int lane = threadIdx.x & 63;
    int b = row_ptr[node], e = row_ptr[node + 1];
    float a0 = 0.f, a1 = 0.f;
    int i = b;
    for (; i + 16 <= e; i += 16) {
        unsigned int p[16];
#pragma unroll
        for (int j = 0; j < 16; ++j)
            p[j] = inh[(size_t)srcs[i + j] * 64 + lane];
#pragma unroll
        for (int j = 0; j < 16; ++j) {
            float u0, u1;
            unpack2h(p[j], u0, u1);
            a0 += u0; a1 += u1;
        }
    }
    int rem = e - i;
    if (rem > 0) {
        int ce = e - 1;
        unsigned int p[16];
#pragma unroll
        for (int j = 0; j < 16; ++j) {
            int idx = i + j;
            if (idx > ce) idx = ce;  // clamped dup loads hit cache; masked below
            p[j] = inh[(size_t)srcs[idx] * 64 + lane];
        }
#pragma unroll
        for (int j = 0; j < 16; ++j) {
            float u0, u1;
            unpack2h(p[j], u0, u1);
            if (j < rem) { a0 += u0; a1 += u1; }
        }
    }
    int deg = e - b;
    float inv = 1.0f / (float)(deg > 0 ? deg : 1);
    oh[(size_t)node * 64 + lane] = pack2h((_Float16)(a0 * inv), (_Float16)(a1 * inv));
}

// ---------------------------------------------------------------------------
// f16 MFMA GEMM, B (hi only) staged in LDS in fragment layout.
// A: single hi plane (agg for k<128, self for k>=128); one MFMA per (ks,n).
template <int NT, int KPS, bool PACKOUT>
__launch_bounds__(256, 4)
__global__ void k_mfma(const unsigned short* __restrict__ A1h,
                       const unsigned short* __restrict__ A2h,
                       const unsigned short* __restrict__ Bthf,
                       const float* __restrict__ bias, float* __restrict__ outf,
                       unsigned short* __restrict__ outh, const int NC) {
    constexpr int STAGE_ELEMS = KPS * NT * 64 * 8;
    constexpr int STAGE_U4 = STAGE_ELEMS / 8;
    __shared__ unsigned short sBh[STAGE_ELEMS];

    const int tid = threadIdx.x;
    const int wave = tid >> 6, lane = tid & 63;
    const int quad = lane >> 4, mr = lane & 15;
    const int m0 = blockIdx.x * 64 + wave * 16;
    const int row = m0 + mr;
    const bool rok = row < NN;

    f32x4 acc[NT] = {};
    const f16x8 zero = {};

    auto aload = [&](int ks) -> f16x8 {
        const int ko = ((ks * 32) & 127) + quad * 8;
        const unsigned short* base = (ks < 4) ? A1h : A2h;
        return rok ? *(const f16x8*)(base + (size_t)row * 128 + ko) : zero;
    };

    f16x8 cah = aload(0), pah;

#pragma unroll
    for (int s = 0; s < 8 / KPS; ++s) {
        const uint4* gh = (const uint4*)(Bthf + (size_t)s * STAGE_ELEMS);
        uint4* lh = (uint4*)sBh;
        if (s) __syncthreads();
        for (int i = tid; i < STAGE_U4; i += 256) lh[i] = gh[i];
        __syncthreads();

#pragma unroll
        for (int kl = 0; kl < KPS; ++kl) {
            const int ks = s * KPS + kl;
            if (ks < 7) pah = aload(ks + 1);
#pragma unroll
            for (int n = 0; n < NT; ++n) {
                const int fo = ((kl * NT + n) * 64 + lane) * 8;
                f16x8 bh = *(const f16x8*)(sBh + fo);
                acc[n] = __builtin_amdgcn_mfma_f32_16x16x32_f16(cah, bh, acc[n], 0, 0, 0);
            }
            cah = pah;
        }
    }

    // Epilogue. C/D layout: col = lane&15, row = quad*4 + reg.
#pragma unroll
    for (int n = 0; n < NT; ++n) {
        int col = n * 16 + mr;
        float bv = (col < NC) ? bias[col] : 0.f;
#pragma unroll
        for (int r = 0; r < 4; ++r) {
            int orow = m0 + quad * 4 + r;
            if (orow < NN && col < NC) {
                float v = acc[n][r] + bv;
                v = v > 0.f ? v : 0.f;
                if (PACKOUT) {
                    union { _Float16 f; unsigned short u; } ch;
                    ch.f = (_Float16)v;
                    outh[(size_t)orow * 128 + col] = ch.u;
                } else {
                    outf[(size_t)orow * NC + col] = v;
                }
            }
        }
    }
}

// ---------------------------------------------------------------------------
// Layer 3 pre-projection: z = h2 @ w3_l (f16, 64-col-padded rows),
//                         y = h2 @ w3_r + b3 (f32, 40 cols). k=128 only.
// Exploits mean-linearity: agg(h2) @ w3_l == agg(h2 @ w3_l).
__global__ __launch_bounds__(256, 4)
void k_gemm3(const unsigned short* __restrict__ Ah,
             const unsigned short* __restrict__ Bthf,
             const float* __restrict__ bias,
             unsigned short* __restrict__ zh, float* __restrict__ yf) {
    __shared__ unsigned short sBh[8 * 3 * 64 * 8];  // 24 KB, all of B
    const int tid = threadIdx.x;
    const int wave = tid >> 6, lane = tid & 63;
    const int quad = lane >> 4, mr = lane & 15;
    const int m0 = blockIdx.x * 64 + wave * 16;
    const int row = m0 + mr;
    const bool rok = row < NN;

    const uint4* gh = (const uint4*)Bthf;
    uint4* lh = (uint4*)sBh;
    for (int i = tid; i < (8 * 3 * 64 * 8) / 8; i += 256) lh[i] = gh[i];

    const f16x8 zero = {};
    f16x8 a[4];
#pragma unroll
    for (int j = 0; j < 4; ++j)
        a[j] = rok ? *(const f16x8*)(Ah + (size_t)row * 128 + j * 32 + quad * 8)
                   : zero;
    __syncthreads();

    f32x4 accl[3] = {}, accr[3] = {};
#pragma unroll
    for (int ks = 0; ks < 4; ++ks) {
#pragma unroll
        for (int n = 0; n < 3; ++n) {
            f16x8 bl = *(const f16x8*)(sBh + ((ks * 3 + n) * 64 + lane) * 8);
            accl[n] = __builtin_amdgcn_mfma_f32_16x16x32_f16(a[ks], bl, accl[n], 0, 0, 0);
            f16x8 br = *(const f16x8*)(sBh + (((ks + 4) * 3 + n) * 64 + lane) * 8);
            accr[n] = __builtin_amdgcn_mfma_f32_16x16x32_f16(a[ks], br, accr[n], 0, 0, 0);
        }
    }

#pragma unroll
    for (int n = 0; n < 3; ++n) {
        int col = n * 16 + mr;
        float bv = (col < NCLS) ? bias[col] : 0.f;
#pragma unroll
        for (int r = 0; r < 4; ++r) {
            int orow = m0 + quad * 4 + r;
            if (orow < NN) {
                union { _Float16 f; unsigned short u; } ch;
                ch.f = (_Float16)accl[n][r];
                zh[(size_t)orow * 64 + col] = ch.u;          // cols >=40 are 0 (B zero-padded)
                if (col < NCLS) yf[(size_t)orow * 40 + col] = accr[n][r] + bv;
            }
        }
    }
}

// ---------------------------------------------------------------------------
// Layer 3 aggregation over projected z (40 f16 = 20 u32, rows padded to
// 128 B): half-wave per node, 16-deep ILP. out = relu(mean + y).
__global__ __launch_bounds__(256, 8)
void k_agg3(const unsigned int* __restrict__ zu,
            const int* __restrict__ row_ptr,
            const int* __restrict__ srcs,
            const float* __restrict__ yf, float* __restrict__ out) {
    const int tid = threadIdx.x;
    const int wave = tid >> 6, lane = tid & 63;
    const int half = lane >> 5, hl = lane & 31;
    const int node = blockIdx.x * 8 + wave * 2 + half;  // 6250*8 == NN exactly
    int b = row_ptr[node], e = row_ptr[node + 1];
    int deg = e - b;
    int od = __shfl_xor(deg, 32);
    int md = max(deg, od);
    int ce = (e > b) ? (e - 1) : b;  // clamp target (deg=0 -> dummy, masked)
    float a0 = 0.f, a1 = 0.f;
    for (int base = 0; base < md; base += 16) {
        unsigned int p[16];
#pragma unroll
        for (int j = 0; j < 16; ++j) {
            int idx = b + base + j;
            if (idx > ce) idx = ce;
            p[j] = zu[(size_t)srcs[idx] * 32 + hl];
        }
#pragma unroll
        for (int j = 0; j < 16; ++j) {
            float u0, u1;
            unpack2h(p[j], u0, u1);
            if (base + j < deg) { a0 += u0; a1 += u1; }
        }
    }
    float inv = 1.0f / (float)(deg > 0 ? deg : 1);
    if (hl < 20) {
        float2 yv = ((const float2*)yf)[(size_t)node * 20 + hl];
        float2 o;
        o.x = fmaxf(a0 * inv + yv.x, 0.f);
        o.y = fmaxf(a1 * inv + yv.y, 0.f);
        ((float2*)out)[(size_t)node * 20 + hl] = o;
    }
}

// ---------------------------------------------------------------------------
extern "C" void kernel_launch(void* const* d_in, const int* in_sizes, int n_in,
                              void* d_out, int out_size, void* d_ws, size_t ws_size,
                              hipStream_t stream) {
    const float* x    = (const float*)d_in[0];
    const int*   ei   = (const int*)d_in[1];
    const float* w1_l = (const float*)d_in[2];
    const float* w1_r = (const float*)d_in[3];
    const float* b1   = (const float*)d_in[4];
    const float* w2_l = (const float*)d_in[5];
    const float* w2_r = (const float*)d_in[6];
    const float* b2   = (const float*)d_in[7];
    const float* w3_l = (const float*)d_in[8];
    const float* w3_r = (const float*)d_in[9];
    const float* b3   = (const float*)d_in[10];
    float* out = (float*)d_out;

    char* w = (char*)d_ws;
    size_t off = 0;
    auto alloc = [&](size_t bytes) -> void* {
        void* p = w + off;
        off += (bytes + 255) / 256 * 256;
        return p;
    };
    int* row_ptr = (int*)alloc((size_t)(NN + 1) * 4);
    int* srcs    = (int*)alloc((size_t)NE * 4);
    int* cellcnt = (int*)alloc((size_t)NBK * PB * 4);
    int* celloff = (int*)alloc((size_t)NBK * PB * 4);
    int* bsum    = (int*)alloc((size_t)NBK * 4);
    unsigned int* pairs = (unsigned int*)alloc((size_t)PB * EPB * 4);
    unsigned short* xh   = (unsigned short*)alloc((size_t)NN * DD * 2);  // also h2h
    unsigned short* aggh = (unsigned short*)alloc((size_t)NN * DD * 2);
    unsigned short* h1h  = (unsigned short*)alloc((size_t)NN * DD * 2);
    unsigned short* zh   = (unsigned short*)alloc((size_t)NN * 64 * 2);
    float*          yf   = (float*)alloc((size_t)NN * 40 * 4);
    unsigned short* bt1h = (unsigned short*)alloc((size_t)8 * 8 * 64 * 8 * 2);
    unsigned short* bt2h = (unsigned short*)alloc((size_t)8 * 8 * 64 * 8 * 2);
    unsigned short* bt3h = (unsigned short*)alloc((size_t)8 * 3 * 64 * 8 * 2);
    unsigned short* h2h = xh;  // x dead after layer-1 GEMM
    (void)ws_size;

    k_front<<<PB + CVB + WB, 256, 0, stream>>>(ei, cellcnt, celloff, pairs, x, xh,
                                               w1_l, w1_r, w2_l, w2_r, w3_l, w3_r,
                                               bt1h, bt2h, bt3h);
    k_scan_ba<<<NBK, 256, 0, stream>>>(cellcnt, bsum);
    k_fill2<<<NBK, 512, 0, stream>>>(pairs, cellcnt, celloff, bsum, row_ptr, srcs);

    const int gmb = (NN + 63) / 64;   // 782 (GEMM m-blocks)
    const int gab = (NN + 3) / 4;     // 12500 (agg blocks, 4 nodes each)
    // Layer 1
    k_agg<<<gab, 256, 0, stream>>>((const unsigned int*)xh, row_ptr, srcs,
                                   (unsigned int*)aggh);
    k_mfma<8, 4, true><<<gmb, 256, 0, stream>>>(aggh, xh, bt1h, b1,
                                                nullptr, h1h, DD);
    // Layer 2 (h2h aliases xh; x is dead)
    k_agg<<<gab, 256, 0, stream>>>((const unsigned int*)h1h, row_ptr, srcs,
                                   (unsigned int*)aggh);
    k_mfma<8, 4, true><<<gmb, 256, 0, stream>>>(aggh, h1h, bt2h, b2,
                                                nullptr, h2h, DD);
    // Layer 3: pre-project then light aggregate
    k_gemm3<<<gmb, 256, 0, stream>>>(h2h, bt3h, b3, zh, yf);
    k_agg3<<<NN / 8, 256, 0, stream>>>((const unsigned int*)zh, row_ptr, srcs,
                                       yf, out);
}